// Round 1
// baseline (127.219 us; speedup 1.0000x reference)
//
#include <hip/hip_runtime.h>

#define IN_F 1024
#define OUT_F 1024
#define NTOK 32768
#define BM 128
#define BN 128
#define BK 32
#define KT (IN_F / BK)  // 32 K-steps

typedef __bf16 bf16;
typedef __bf16 bf16x4 __attribute__((ext_vector_type(4)));
typedef __bf16 bf16x8 __attribute__((ext_vector_type(8)));
typedef float f32x4 __attribute__((ext_vector_type(4)));

// ---------------------------------------------------------------------------
// Kernel 1: build patched bf16 weight W'.
//   W'[row, src]   = 0.25*(w[row,src] + w[row,c0] + w[row,c1] + w[row,c2])
//   W'[row, ck]    = 0
//   W'[row, other] = w[row, other]
// One block per rewire index r (rewire_rows is a permutation: arange).
// ---------------------------------------------------------------------------
__global__ void build_wp(const float* __restrict__ W,
                         const int* __restrict__ rows,
                         const int* __restrict__ srcs,
                         const int* __restrict__ clones,
                         bf16* __restrict__ Wp) {
  const int r = blockIdx.x;
  const int row = rows[r];
  const int s = srcs[r];
  const int c0 = clones[3 * r + 0];
  const int c1 = clones[3 * r + 1];
  const int c2 = clones[3 * r + 2];
  const float* wr = W + (size_t)row * IN_F;
  const float fixv = 0.25f * (wr[s] + wr[c0] + wr[c1] + wr[c2]);

  const int col = threadIdx.x * 4;  // 256 threads * 4 cols = 1024
  f32x4 v = *reinterpret_cast<const f32x4*>(wr + col);
  bf16x4 o;
#pragma unroll
  for (int j = 0; j < 4; ++j) {
    const int c = col + j;
    float f = v[j];
    if (c == c0 || c == c1 || c == c2) f = 0.0f;
    if (c == s) f = fixv;
    o[j] = (bf16)f;
  }
  *reinterpret_cast<bf16x4*>(Wp + (size_t)row * IN_F + col) = o;
}

// ---------------------------------------------------------------------------
// Kernel 2: out = X(bf16-converted on the fly) @ W'^T + bias
// 128x128 tile, BK=32, 4 waves (2x2), 16x16x32 bf16 MFMA, 4x4 frags/wave.
// A: reg-staged fp32->bf16 (prefetched one K-step ahead).
// B: global_load_lds width 16 (already bf16).
// ---------------------------------------------------------------------------
__device__ __forceinline__ void load_a(const float* __restrict__ gA, int kt,
                                       f32x4* dst) {
#pragma unroll
  for (int j = 0; j < 4; ++j)
    dst[j] = *reinterpret_cast<const f32x4*>(gA + (size_t)(j * 32) * IN_F +
                                             kt * BK);
}

__global__ __launch_bounds__(256, 3) void gemm_rewire(
    const float* __restrict__ X, const bf16* __restrict__ Wp,
    const float* __restrict__ bias, float* __restrict__ out) {
  __shared__ __align__(16) bf16 lA[BM * BK];  // [128 rows][32 k]
  __shared__ __align__(16) bf16 lB[BN * BK];  // [128 cols][32 k]

  const int tid = threadIdx.x;
  const int lane = tid & 63;
  const int w = tid >> 6;        // wave 0..3
  const int wr = w >> 1;         // wave row 0..1 (64 rows each)
  const int wc = w & 1;          // wave col 0..1 (64 cols each)
  const int bm = blockIdx.x;     // 0..255
  const int bn = blockIdx.y;     // 0..7

  // --- A staging addressing: thread t loads 4x float4; load j covers tile
  // row j*32 + t/8, cols (t%8)*4 .. +4 (fp32). 8 lanes = 128B contiguous.
  const int ar = tid >> 3;        // 0..31
  const int ac = (tid & 7) * 4;   // 0..28
  const float* gA = X + ((size_t)bm * BM + ar) * IN_F + ac;

  // --- B staging addressing (global_load_lds, 16B/lane):
  // issue i, wave w covers LDS bytes i*4096 + w*1024 + lane*16
  //   -> row = i*64 + w*16 + lane/4, col = (lane&3)*8 (bf16 elements)
  const int brow = w * 16 + (lane >> 2);
  const int bcol = (lane & 3) * 8;
  const bf16* gB = Wp + ((size_t)bn * BN + brow) * IN_F + bcol;
  bf16* lB_base = lB + w * 512;  // elements; +2048 for issue 1

  // --- accumulators, pre-loaded with bias (each (m,n,reg) is one output elem)
  f32x4 acc[4][4];
#pragma unroll
  for (int n = 0; n < 4; ++n) {
    const float bv = bias[bn * BN + wc * 64 + n * 16 + (lane & 15)];
#pragma unroll
    for (int m = 0; m < 4; ++m) acc[m][n] = (f32x4){bv, bv, bv, bv};
  }

  // --- fragment read offsets (elements):
  // A frag m: lane reads lA[(wr*64 + m*16 + (lane&15))*BK + (lane>>4)*8 ..+8]
  const int afoff = (wr * 64 + (lane & 15)) * BK + (lane >> 4) * 8;
  const int bfoff = (wc * 64 + (lane & 15)) * BK + (lane >> 4) * 8;

  f32x4 av[4];
  load_a(gA, 0, av);

  for (int kt = 0; kt < KT; ++kt) {
    if (kt > 0) __syncthreads();  // previous compute done -> LDS reusable

    // A: convert + ds_write (waits the prefetched global loads)
#pragma unroll
    for (int j = 0; j < 4; ++j) {
      bf16x4 o;
      o[0] = (bf16)av[j][0];
      o[1] = (bf16)av[j][1];
      o[2] = (bf16)av[j][2];
      o[3] = (bf16)av[j][3];
      *reinterpret_cast<bf16x4*>(lA + (j * 32 + ar) * BK + ac) = o;
    }

    // B: async global -> LDS, 2 issues per wave
    const bf16* gBk = gB + kt * BK;
    __builtin_amdgcn_global_load_lds(
        (const __attribute__((address_space(1))) void*)gBk,
        (__attribute__((address_space(3))) void*)lB_base, 16, 0, 0);
    __builtin_amdgcn_global_load_lds(
        (const __attribute__((address_space(1))) void*)(gBk + (size_t)64 * IN_F),
        (__attribute__((address_space(3))) void*)(lB_base + 2048), 16, 0, 0);

    __syncthreads();  // staging visible (compiler drains vmcnt/lgkmcnt)

    // prefetch next A tile into regs; latency hides under MFMA below
    const bool pf = (kt + 1) < KT;
    f32x4 avn[4];
    if (pf) load_a(gA, kt + 1, avn);

    bf16x8 af[4], bfr[4];
#pragma unroll
    for (int m = 0; m < 4; ++m)
      af[m] = *reinterpret_cast<const bf16x8*>(lA + afoff + m * 16 * BK);
#pragma unroll
    for (int n = 0; n < 4; ++n)
      bfr[n] = *reinterpret_cast<const bf16x8*>(lB + bfoff + n * 16 * BK);

#pragma unroll
    for (int m = 0; m < 4; ++m)
#pragma unroll
      for (int n = 0; n < 4; ++n)
        acc[m][n] = __builtin_amdgcn_mfma_f32_16x16x32_bf16(af[m], bfr[n],
                                                            acc[m][n], 0, 0, 0);

    if (pf) {
#pragma unroll
      for (int j = 0; j < 4; ++j) av[j] = avn[j];
    }
  }

  // --- epilogue: C/D layout col = lane&15, row = (lane>>4)*4 + i
  const int orow0 = bm * BM + wr * 64 + (lane >> 4) * 4;
  const int ocol0 = bn * BN + wc * 64 + (lane & 15);
#pragma unroll
  for (int m = 0; m < 4; ++m) {
#pragma unroll
    for (int n = 0; n < 4; ++n) {
      const f32x4 v = acc[m][n];
      const size_t base = (size_t)(orow0 + m * 16) * OUT_F + (ocol0 + n * 16);
#pragma unroll
      for (int i = 0; i < 4; ++i) out[base + (size_t)i * OUT_F] = v[i];
    }
  }
}

// ---------------------------------------------------------------------------
extern "C" void kernel_launch(void* const* d_in, const int* in_sizes, int n_in,
                              void* d_out, int out_size, void* d_ws,
                              size_t ws_size, hipStream_t stream) {
  const float* x = (const float*)d_in[0];
  const float* weight = (const float*)d_in[1];
  const float* bias = (const float*)d_in[2];
  const int* rrows = (const int*)d_in[3];
  const int* rsrc = (const int*)d_in[4];
  const int* rclones = (const int*)d_in[5];
  float* out = (float*)d_out;
  bf16* Wp = (bf16*)d_ws;  // 1024*1024*2 = 2 MB scratch

  build_wp<<<dim3(OUT_F), dim3(256), 0, stream>>>(weight, rrows, rsrc, rclones,
                                                  Wp);
  gemm_rewire<<<dim3(NTOK / BM, OUT_F / BN), dim3(256), 0, stream>>>(x, Wp,
                                                                     bias, out);
}